// Round 6
// baseline (450.242 us; speedup 1.0000x reference)
//
#include <hip/hip_runtime.h>

#define SLOPE 0.01f
#define EPSV  1e-5f
#define BB    64
#define NN    500
#define TT    50
#define E_N   16000
#define FF    43
#define PP    500
#define HH    128
#define XSTRIDE 48

typedef const float* fp;

__device__ __forceinline__ float lrelu(float x){ return x >= 0.f ? x : SLOPE * x; }
__device__ __forceinline__ float bnap(float x, fp bnp, int c, int C){
  float g  = bnp[c], b_ = bnp[C + c];
  float m  = bnp[2*C + c], v = bnp[3*C + c];
  float s = g * rsqrtf(v + EPSV);
  return x * s + (b_ - m * s);
}

// ---------------- Kernel A: fused temporal feature extractor ----------------
// one wave per (b,n); writes x[b,n,0:43] (f32, stride 48)
__global__ __launch_bounds__(64) void k_temporal_r6(
    fp obs, fp sc1w, fp sc1b, fp sbn1, fp sc2w, fp sc2b, fp sbn2,
    fp mc1w, fp mc1b, fp mbn1, fp mc2w, fp mc2b, fp mbn2,
    float* __restrict__ xbuf)
{
  int b = blockIdx.x / NN, n = blockIdx.x % NN;
  int lane = threadIdx.x;
  __shared__ float obs_s[3][52];
  __shared__ float s1[3][48];
  __shared__ float m1[3][30];

  for (int i = lane; i < 150; i += 64){
    int c = i / 50, t = i % 50;
    obs_s[c][t] = obs[((b*3 + c)*NN + n)*TT + t];
  }
  __syncthreads();

  for (int i = lane; i < 234; i += 64){
    if (i < 144){
      int co = i / 48, t = i % 48;
      float acc = sc1b[co];
      for (int ci = 0; ci < 3; ci++)
        for (int k = 0; k < 3; k++)
          acc += obs_s[ci][t + k] * sc1w[co*9 + ci*3 + k];
      s1[co][t] = lrelu(bnap(acc, sbn1, co, 3));
    } else {
      int j = i - 144;
      int co = j / 30, t = j % 30;
      float acc = mc1b[co];
      for (int ci = 0; ci < 3; ci++)
        for (int k = 0; k < 21; k++)
          acc += obs_s[ci][t + k] * mc1w[co*63 + ci*21 + k];
      m1[co][t] = lrelu(bnap(acc, mbn1, co, 3));
    }
  }
  __syncthreads();

  float val = 0.f;
  if (lane < 20){
    float acc = sc2b[lane];
    for (int ci = 0; ci < 3; ci++)
      for (int k = 0; k < 48; k++)
        acc += s1[ci][k] * sc2w[lane*144 + ci*48 + k];
    val = lrelu(bnap(acc, sbn2, lane, 20));
  } else if (lane < 40){
    int co = lane - 20;
    float acc = mc2b[co];
    for (int ci = 0; ci < 3; ci++)
      for (int k = 0; k < 30; k++)
        acc += m1[ci][k] * mc2w[co*90 + ci*30 + k];
    val = lrelu(bnap(acc, mbn2, co, 20));
  } else if (lane < FF){
    int c = lane - 40;
    float mx = obs_s[c][0];
    for (int t = 1; t < 50; t++) mx = fmaxf(mx, obs_s[c][t]);
    val = lrelu(mx);
  }
  if (lane < FF) xbuf[(b*NN + n)*XSTRIDE + lane] = val;
}

// ---------------- Kernel B0: build dst-CSR + per-relation degrees ----------------
__global__ __launch_bounds__(1024) void k_csr_r6(
    const int* __restrict__ ei, const int* __restrict__ et,
    int* __restrict__ deg, int* __restrict__ offs, int* __restrict__ cursor,
    int* __restrict__ e_src, int* __restrict__ e_typ)
{
  int tid = threadIdx.x;
  __shared__ int cnt_s[512];
  __shared__ int scan_s[512];
  for (int i = tid; i < 4*NN; i += 1024) deg[i] = 0;
  for (int i = tid; i < NN;   i += 1024) cursor[i] = 0;
  if (tid < 512) cnt_s[tid] = 0;
  __syncthreads();
  for (int e = tid; e < E_N; e += 1024){
    int d = ei[E_N + e]; int r = et[e];
    atomicAdd(&cnt_s[d], 1);
    atomicAdd(&deg[r*NN + d], 1);
  }
  __syncthreads();
  if (tid < 512) scan_s[tid] = cnt_s[tid];
  __syncthreads();
  for (int off = 1; off < 512; off <<= 1){
    int v = 0;
    if (tid < 512 && tid >= off) v = scan_s[tid - off];
    __syncthreads();
    if (tid < 512) scan_s[tid] += v;
    __syncthreads();
  }
  if (tid <= NN) offs[tid] = (tid == 0) ? 0 : scan_s[tid - 1];
  __syncthreads();
  for (int e = tid; e < E_N; e += 1024){
    int s = ei[e]; int d = ei[E_N + e]; int r = et[e];
    int pos = atomicAdd(&cursor[d], 1);
    int idx = offs[d] + pos;
    e_src[idx] = s; e_typ[idx] = r;
  }
}

// ---------------- Kernel B: relational GCN layer ----------------
__global__ __launch_bounds__(64) void k_graph_r6(
    const float* __restrict__ xbuf, fp gwroot, fp gwrel, fp gb, fp gbnp,
    const int* __restrict__ deg, const int* __restrict__ offs,
    const int* __restrict__ e_src, const int* __restrict__ e_typ,
    float* __restrict__ gbuf)
{
  int b = blockIdx.x / NN, n = blockIdx.x % NN;
  int lane = threadIdx.x;
  __shared__ float xs[5][44];
  const float* xb = xbuf + (size_t)b*NN*XSTRIDE;
  float a0=0.f, a1=0.f, a2=0.f, a3=0.f, xv=0.f;
  if (lane < FF) xv = xb[n*XSTRIDE + lane];
  int beg = offs[n], end = offs[n+1];
  for (int i = beg; i < end; i++){
    int s = e_src[i], r = e_typ[i];
    float v = (lane < FF) ? xb[s*XSTRIDE + lane] : 0.f;
    a0 += (r == 0) ? v : 0.f;
    a1 += (r == 1) ? v : 0.f;
    a2 += (r == 2) ? v : 0.f;
    a3 += (r == 3) ? v : 0.f;
  }
  if (lane < FF){
    xs[0][lane] = xv;
    xs[1][lane] = a0 / fmaxf((float)deg[0*NN + n], 1.f);
    xs[2][lane] = a1 / fmaxf((float)deg[1*NN + n], 1.f);
    xs[3][lane] = a2 / fmaxf((float)deg[2*NN + n], 1.f);
    xs[4][lane] = a3 / fmaxf((float)deg[3*NN + n], 1.f);
  }
  __syncthreads();
  if (lane < FF){
    int g = lane;
    float acc = gb[g];
    for (int f = 0; f < FF; f++) acc += xs[0][f] * gwroot[f*FF + g];
    for (int r = 0; r < 4; r++)
      for (int f = 0; f < FF; f++)
        acc += xs[1+r][f] * gwrel[(r*FF + f)*FF + g];
    acc = lrelu(bnap(acc, gbnp, g, FF));
    gbuf[(b*NN + n)*XSTRIDE + g] = acc;
  }
}

// ---------------- Kernel C: head (logits -> MLP -> softmax), f32 output ------
__global__ __launch_bounds__(512) void k_head_r6(
    const float* __restrict__ xbuf, const float* __restrict__ gbuf,
    fp action, const int* __restrict__ nts,
    fp acw, fp acb, fp aw1, fp ab1, fp aw2, fp ab2, fp aw3, fp ab3,
    float* __restrict__ out)
{
  int b = blockIdx.x;
  int tid = threadIdx.x;
  __shared__ float o[PP+1];
  __shared__ float h1[HH];
  __shared__ float h2[HH];
  __shared__ float red[512];

  if (tid < PP){
    int np = nts[tid];
    const float* xr = xbuf + (size_t)(b*NN + np)*XSTRIDE;
    const float* gr = gbuf + (size_t)(b*NN + np)*XSTRIDE;
    float acc = acb[0] + action[b*(PP+1) + 1 + tid] * acw[0];
    for (int c = 0; c < FF; c++) acc += xr[c] * acw[1 + c];
    for (int c = 0; c < FF; c++) acc += gr[c] * acw[1 + FF + c];
    o[1 + tid] = acc;
  }
  if (tid == 511) o[0] = 0.f;
  __syncthreads();

  if (tid < HH){
    float acc = ab1[tid];
    for (int k = 0; k <= PP; k++) acc += o[k] * aw1[k*HH + tid];
    h1[tid] = fmaxf(acc, 0.f);
  }
  __syncthreads();
  if (tid < HH){
    float acc = ab2[tid];
    for (int k = 0; k < HH; k++) acc += h1[k] * aw2[k*HH + tid];
    h2[tid] = fmaxf(acc, 0.f);
  }
  __syncthreads();

  float val = -1e30f;
  if (tid <= PP){
    float acc = ab3[tid];
    for (int k = 0; k < HH; k++) acc += h2[k] * aw3[k*(PP+1) + tid];
    val = acc;
  }
  red[tid] = val;
  __syncthreads();
  for (int s = 256; s > 0; s >>= 1){
    if (tid < s) red[tid] = fmaxf(red[tid], red[tid + s]);
    __syncthreads();
  }
  float mx = red[0];
  __syncthreads();
  float e = (tid <= PP) ? expf(val - mx) : 0.f;
  red[tid] = e;
  __syncthreads();
  for (int s = 256; s > 0; s >>= 1){
    if (tid < s) red[tid] += red[tid + s];
    __syncthreads();
  }
  float sum = red[0];
  if (tid <= PP) out[b*(PP+1) + tid] = e / sum;   // f32 store — the fix
}

extern "C" void kernel_launch(void* const* d_in, const int* in_sizes, int n_in,
                              void* d_out, int out_size, void* d_ws, size_t ws_size,
                              hipStream_t stream)
{
  fp obs    = (fp)d_in[0];
  fp action = (fp)d_in[1];
  const int* ei  = (const int*)d_in[2];
  const int* et  = (const int*)d_in[3];
  const int* nts = (const int*)d_in[4];
  fp sc1w=(fp)d_in[5],  sc1b=(fp)d_in[6],  sbn1=(fp)d_in[7];
  fp sc2w=(fp)d_in[8],  sc2b=(fp)d_in[9],  sbn2=(fp)d_in[10];
  fp mc1w=(fp)d_in[11], mc1b=(fp)d_in[12], mbn1=(fp)d_in[13];
  fp mc2w=(fp)d_in[14], mc2b=(fp)d_in[15], mbn2=(fp)d_in[16];
  fp gwroot=(fp)d_in[17], gwrel=(fp)d_in[18], gb=(fp)d_in[19], gbnp=(fp)d_in[20];
  fp acw=(fp)d_in[21], acb=(fp)d_in[22];
  fp aw1=(fp)d_in[23], ab1=(fp)d_in[24];
  fp aw2=(fp)d_in[25], ab2=(fp)d_in[26];
  fp aw3=(fp)d_in[27], ab3=(fp)d_in[28];

  float* xbuf = (float*)d_ws;                       // 64*500*48 f32
  float* gbuf = xbuf + (size_t)BB*NN*XSTRIDE;       // 64*500*48 f32
  int*   ib   = (int*)(gbuf + (size_t)BB*NN*XSTRIDE);
  int* deg    = ib;                 // 4*500
  int* offs   = ib + 2000;          // 501
  int* cursor = ib + 2501;          // 500
  int* e_src  = ib + 3001;          // 16000
  int* e_typ  = ib + 3001 + E_N;    // 16000

  float* out = (float*)d_out;

  hipLaunchKernelGGL(k_temporal_r6, dim3(BB*NN), dim3(64), 0, stream,
    obs, sc1w, sc1b, sbn1, sc2w, sc2b, sbn2,
    mc1w, mc1b, mbn1, mc2w, mc2b, mbn2, xbuf);
  hipLaunchKernelGGL(k_csr_r6, dim3(1), dim3(1024), 0, stream,
    ei, et, deg, offs, cursor, e_src, e_typ);
  hipLaunchKernelGGL(k_graph_r6, dim3(BB*NN), dim3(64), 0, stream,
    xbuf, gwroot, gwrel, gb, gbnp, deg, offs, e_src, e_typ, gbuf);
  hipLaunchKernelGGL(k_head_r6, dim3(BB), dim3(512), 0, stream,
    xbuf, gbuf, action, nts, acw, acb, aw1, ab1, aw2, ab2, aw3, ab3, out);
}